// Round 7
// baseline (35.439 us; speedup 1.0000x reference)
//
#include <hip/hip_runtime.h>
#include <hip/hip_bf16.h>
#include <math.h>

// Problem constants (fixed by reference): N=2000 nodes, B=2000 bills, D=32, K=3.
#define NN    2000
#define NB    2000
#define DD    32
#define NP    8                       // politicians per block
#define TPB   64                      // one wave per block; bills = lanes
#define GX    ((NB + TPB - 1) / TPB)  // 32
#define GY    (NN / NP)               // 250
#define NPART (GX * GY)               // 8000 partials

// d_ws layout: [0, 256KB) zbT4 = float4[DD/4][NB]; [256KB, +32KB) partials.
#define ZBT_ELEMS ((DD / 4) * NB)     // 16000 float4s

// Transpose+pack zb [B][D] -> zbT4[d4][b] (float4 of dims 4d4..4d4+3).
// Makes the main kernel's per-lane bill-row fill perfectly coalesced.
__global__ __launch_bounds__(256) void pol2vec_transpose(
    const float* __restrict__ zb, float4* __restrict__ zbT4)
{
    const int u = blockIdx.x * 256 + threadIdx.x;
    if (u < ZBT_ELEMS) {
        const int d4 = u / NB;
        const int b  = u - d4 * NB;
        zbT4[u] = *(const float4*)(zb + (size_t)b * DD + 4 * d4);
    }
}

// Main: lanes = bills (all per-lane streams coalesced), politicians = uniform
// loop (zp/gamma scalarize to s_load). No LDS, no atomics, no memset.
__global__ __launch_bounds__(TPB, 4) void pol2vec_main(
    const int*    __restrict__ events,  // [N,B] 0/1
    const float*  __restrict__ tarr,    // [B]
    const float*  __restrict__ beta,    // [B]
    const float*  __restrict__ gamma,   // [N]
    const float*  __restrict__ zp,      // [K,N,D]
    const float4* __restrict__ zbT4,    // [DD/4][NB] packed transpose
    float*        __restrict__ partials)// [NPART]
{
    const int lane = threadIdx.x;
    const int b    = blockIdx.x * TPB + lane;
    const int n0   = blockIdx.y * NP;
    const bool valid = (b < NB);
    const int bc   = valid ? b : NB - 1;   // clamp; masked at the end

    // Per-lane bill state (coalesced).
    const float t   = tarr[bc];
    const float bb  = beta[bc];
    const float t2h = 0.5f * t * t;        // t^2 / 2!

    // Own zb row via transposed layout: 8 coalesced float4 loads -> 32 VGPRs.
    float zr[DD];
#pragma unroll
    for (int i = 0; i < DD / 4; ++i) {
        const float4 v = zbT4[i * NB + bc];
        zr[4 * i + 0] = v.x; zr[4 * i + 1] = v.y;
        zr[4 * i + 2] = v.z; zr[4 * i + 3] = v.w;
    }
#pragma unroll
    for (int d = 0; d < DD; ++d) asm volatile("" : "+v"(zr[d]));  // pin

    // Prefetch all NP event words (independent coalesced loads, one latency).
    float sg[NP];
#pragma unroll
    for (int j = 0; j < NP; ++j) {
        sg[j] = (events[(size_t)(n0 + j) * NB + bc] != 0) ? 1.f : -1.f;
    }

    float acc = 0.f;

#pragma unroll 2
    for (int j = 0; j < NP; ++j) {
        const int n = n0 + j;
        const float g = gamma[n];                                  // s_load
        const float4* pA = (const float4*)(zp + (size_t)n * DD);   // uniform
        const float4* pB = (const float4*)(zp + ((size_t)NN + n) * DD);
        const float4* pC = (const float4*)(zp + ((size_t)2 * NN + n) * DD);

        float d2a = 0.f, d2b = 0.f, d2c = 0.f, d2d = 0.f;
#pragma unroll
        for (int i = 0; i < DD / 4; ++i) {
            const float4 a  = pA[i];
            const float4 bv = pB[i];
            const float4 cv = pC[i];
            // pos = A + t*B + (t^2/2)*C
            float p0 = fmaf(t2h, cv.x, fmaf(t, bv.x, a.x));
            float p1 = fmaf(t2h, cv.y, fmaf(t, bv.y, a.y));
            float p2 = fmaf(t2h, cv.z, fmaf(t, bv.z, a.z));
            float p3 = fmaf(t2h, cv.w, fmaf(t, bv.w, a.w));
            float f0 = p0 - zr[4 * i + 0];
            float f1 = p1 - zr[4 * i + 1];
            float f2 = p2 - zr[4 * i + 2];
            float f3 = p3 - zr[4 * i + 3];
            d2a = fmaf(f0, f0, d2a);
            d2b = fmaf(f1, f1, d2b);
            d2c = fmaf(f2, f2, d2c);
            d2d = fmaf(f3, f3, d2d);
        }
        const float d2 = (d2a + d2b) + (d2c + d2d);
        const float L  = g + bb - sqrtf(d2);
        const float s  = sg[j] * L;
        // -log_sigmoid(s) = max(-s,0) + log(1+exp(-|s|)); hw exp/log.
        acc += fmaxf(-s, 0.f) + __logf(1.f + __expf(-fabsf(s)));
    }

    if (!valid) acc = 0.f;

    // Single-wave block: shuffle reduce, lane 0 writes its partial slot.
#pragma unroll
    for (int o = 32; o > 0; o >>= 1) acc += __shfl_down(acc, o, 64);
    if (lane == 0) partials[blockIdx.y * GX + blockIdx.x] = acc;
}

// 8000 partials -> d_out[0] (overwrite; poison-proof).
__global__ __launch_bounds__(256) void pol2vec_reduce(
    const float4* __restrict__ partials4, float* __restrict__ out)
{
    __shared__ float s_red[4];
    const int tid = threadIdx.x;
    float s = 0.f;
    for (int i = tid; i < NPART / 4; i += 256) {
        const float4 v = partials4[i];
        s += (v.x + v.y) + (v.z + v.w);
    }
#pragma unroll
    for (int o = 32; o > 0; o >>= 1) s += __shfl_down(s, o, 64);
    if ((tid & 63) == 0) s_red[tid >> 6] = s;
    __syncthreads();
    if (tid == 0) out[0] = (s_red[0] + s_red[1]) + (s_red[2] + s_red[3]);
}

extern "C" void kernel_launch(void* const* d_in, const int* in_sizes, int n_in,
                              void* d_out, int out_size, void* d_ws, size_t ws_size,
                              hipStream_t stream) {
    const int*   events = (const int*)d_in[0];    // [N,B]
    const float* tarr   = (const float*)d_in[1];  // [B]
    const float* beta   = (const float*)d_in[2];  // [B]
    const float* gamma  = (const float*)d_in[3];  // [N]
    const float* zb     = (const float*)d_in[4];  // [B,D]
    const float* zp     = (const float*)d_in[5];  // [K,N,D]
    float* out = (float*)d_out;

    float4* zbT4     = (float4*)d_ws;                           // 256 KB
    float*  partials = (float*)((char*)d_ws + ZBT_ELEMS * 16);  // 32 KB

    pol2vec_transpose<<<(ZBT_ELEMS + 255) / 256, 256, 0, stream>>>(zb, zbT4);
    dim3 grid(GX, GY);
    pol2vec_main<<<grid, TPB, 0, stream>>>(events, tarr, beta, gamma, zp,
                                           zbT4, partials);
    pol2vec_reduce<<<1, 256, 0, stream>>>((const float4*)partials, out);
}

// Round 8
// 32.511 us; speedup vs baseline: 1.0901x; 1.0901x over previous
//
#include <hip/hip_runtime.h>
#include <hip/hip_bf16.h>
#include <math.h>

// Problem constants (fixed by reference): N=2000 nodes, B=2000 bills, D=32, K=3.
#define NN    2000
#define NB    2000
#define DD    32
#define NP    8                       // politicians per block
#define TPB   64                      // one wave per block; bills = lanes
#define GX    ((NB + TPB - 1) / TPB)  // 32
#define GY    (NN / NP)               // 250
#define NPART (GX * GY)               // 8000 partials

// d_ws layout:
//   [0, 256KB)        zbT4   = float4[DD/4][NB]   (transposed bill embeddings)
//   [256KB, +64KB)    coeffs = float[NN][8]       {c0..c4, gamma, pad, pad}
//   [320KB, +32KB)    partials[NPART]
#define ZBT_ELEMS ((DD / 4) * NB)     // 16000 float4s
#define COEF_OFF  (ZBT_ELEMS * 16)    // bytes
#define PART_OFF  (COEF_OFF + NN * 8 * 4)

// Prep: (a) transpose zb [B][D] -> zbT4[d4][b]; (b) per-politician polynomial
// coefficients of |pos(t)|^2 = c0 + c1 t + c2 t^2 + c3 t^3 + c4 t^4, with
// pos = A + tB + (t^2/2)C:
//   c0=|A|^2, c1=2A.B, c2=|B|^2+A.C, c3=B.C, c4=|C|^2/4.  Slot 5 = gamma.
__global__ __launch_bounds__(256) void pol2vec_prep(
    const float* __restrict__ zb, const float* __restrict__ zp,
    const float* __restrict__ gamma,
    float4* __restrict__ zbT4, float* __restrict__ coeffs)
{
    const int u = blockIdx.x * 256 + threadIdx.x;
    if (u < ZBT_ELEMS) {
        const int d4 = u / NB;
        const int b  = u - d4 * NB;
        zbT4[u] = *(const float4*)(zb + (size_t)b * DD + 4 * d4);
    } else if (u < ZBT_ELEMS + NN) {
        const int n = u - ZBT_ELEMS;
        const float* pA = zp + (size_t)n * DD;
        const float* pB = zp + ((size_t)NN + n) * DD;
        const float* pC = zp + ((size_t)2 * NN + n) * DD;
        float aa = 0.f, ab = 0.f, ac = 0.f, bbb = 0.f, bc = 0.f, cc = 0.f;
#pragma unroll
        for (int d = 0; d < DD; ++d) {
            const float a = pA[d], b = pB[d], c = pC[d];
            aa = fmaf(a, a, aa);  ab = fmaf(a, b, ab);  ac = fmaf(a, c, ac);
            bbb = fmaf(b, b, bbb); bc = fmaf(b, c, bc); cc = fmaf(c, c, cc);
        }
        float* o = coeffs + 8 * n;
        o[0] = aa;             o[1] = 2.f * ab;
        o[2] = bbb + ac;       o[3] = bc;
        o[4] = 0.25f * cc;     o[5] = gamma[n];
        o[6] = 0.f;            o[7] = 0.f;
    }
}

// Main: lanes = bills. Per pair: dot = A.z + t B.z + (t^2/2) C.z (3 pure-FMA
// dots, uniform zp -> s_load), dist^2 = poly_n(t) - 2 dot + |zb|^2.
__global__ __launch_bounds__(TPB, 4) void pol2vec_main(
    const int*    __restrict__ events,  // [N,B] 0/1
    const float*  __restrict__ tarr,    // [B]
    const float*  __restrict__ beta,    // [B]
    const float*  __restrict__ zp,      // [K,N,D]
    const float4* __restrict__ zbT4,    // [DD/4][NB]
    const float*  __restrict__ coeffs,  // [NN][8]
    float*        __restrict__ partials)// [NPART]
{
    const int lane = threadIdx.x;
    const int b    = blockIdx.x * TPB + lane;
    const int n0   = blockIdx.y * NP;
    const bool valid = (b < NB);
    const int bc   = valid ? b : NB - 1;   // clamp; masked at the end

    const float t   = tarr[bc];
    const float bb  = beta[bc];
    const float t2h = 0.5f * t * t;

    // Own zb row via transposed layout: 8 coalesced float4 loads -> 32 VGPRs.
    float zr[DD];
#pragma unroll
    for (int i = 0; i < DD / 4; ++i) {
        const float4 v = zbT4[i * NB + bc];
        zr[4 * i + 0] = v.x; zr[4 * i + 1] = v.y;
        zr[4 * i + 2] = v.z; zr[4 * i + 3] = v.w;
    }
#pragma unroll
    for (int d = 0; d < DD; ++d) asm volatile("" : "+v"(zr[d]));  // pin

    float z2 = 0.f;
#pragma unroll
    for (int d = 0; d < DD; ++d) z2 = fmaf(zr[d], zr[d], z2);

    // Prefetch all NP event words (independent coalesced loads, one latency).
    float sg[NP];
#pragma unroll
    for (int j = 0; j < NP; ++j) {
        sg[j] = (events[(size_t)(n0 + j) * NB + bc] != 0) ? 1.f : -1.f;
    }

    float acc = 0.f;

#pragma unroll 2
    for (int j = 0; j < NP; ++j) {
        const int n = n0 + j;
        const float* cc = coeffs + 8 * n;                          // s_load x8
        const float4* pA = (const float4*)(zp + (size_t)n * DD);   // uniform
        const float4* pB = (const float4*)(zp + ((size_t)NN + n) * DD);
        const float4* pC = (const float4*)(zp + ((size_t)2 * NN + n) * DD);

        float da0 = 0.f, da1 = 0.f, db0 = 0.f, db1 = 0.f, dc0 = 0.f, dc1 = 0.f;
#pragma unroll
        for (int i = 0; i < DD / 4; ++i) {
            const float4 A = pA[i];
            const float4 B = pB[i];
            const float4 C = pC[i];
            const float z0 = zr[4 * i + 0], z1 = zr[4 * i + 1];
            const float z2e = zr[4 * i + 2], z3 = zr[4 * i + 3];
            da0 = fmaf(A.x, z0, da0); da1 = fmaf(A.y, z1, da1);
            da0 = fmaf(A.z, z2e, da0); da1 = fmaf(A.w, z3, da1);
            db0 = fmaf(B.x, z0, db0); db1 = fmaf(B.y, z1, db1);
            db0 = fmaf(B.z, z2e, db0); db1 = fmaf(B.w, z3, db1);
            dc0 = fmaf(C.x, z0, dc0); dc1 = fmaf(C.y, z1, dc1);
            dc0 = fmaf(C.z, z2e, dc0); dc1 = fmaf(C.w, z3, dc1);
        }
        const float dot = fmaf(t2h, dc0 + dc1, fmaf(t, db0 + db1, da0 + da1));
        // |pos|^2 via Horner in t.
        const float pv = fmaf(t, fmaf(t, fmaf(t, fmaf(t, cc[4], cc[3]),
                                              cc[2]), cc[1]), cc[0]);
        const float d2 = fmaxf(fmaf(-2.f, dot, pv + z2), 0.f);
        const float L  = cc[5] + bb - sqrtf(d2);
        const float s  = sg[j] * L;
        // -log_sigmoid(s) = max(-s,0) + log(1+exp(-|s|)); hw exp/log.
        acc += fmaxf(-s, 0.f) + __logf(1.f + __expf(-fabsf(s)));
    }

    if (!valid) acc = 0.f;

    // Single-wave block: shuffle reduce, lane 0 writes its partial slot.
#pragma unroll
    for (int o = 32; o > 0; o >>= 1) acc += __shfl_down(acc, o, 64);
    if (lane == 0) partials[blockIdx.y * GX + blockIdx.x] = acc;
}

// 8000 partials -> d_out[0] (overwrite; poison-proof).
__global__ __launch_bounds__(256) void pol2vec_reduce(
    const float4* __restrict__ partials4, float* __restrict__ out)
{
    __shared__ float s_red[4];
    const int tid = threadIdx.x;
    float s = 0.f;
    for (int i = tid; i < NPART / 4; i += 256) {
        const float4 v = partials4[i];
        s += (v.x + v.y) + (v.z + v.w);
    }
#pragma unroll
    for (int o = 32; o > 0; o >>= 1) s += __shfl_down(s, o, 64);
    if ((tid & 63) == 0) s_red[tid >> 6] = s;
    __syncthreads();
    if (tid == 0) out[0] = (s_red[0] + s_red[1]) + (s_red[2] + s_red[3]);
}

extern "C" void kernel_launch(void* const* d_in, const int* in_sizes, int n_in,
                              void* d_out, int out_size, void* d_ws, size_t ws_size,
                              hipStream_t stream) {
    const int*   events = (const int*)d_in[0];    // [N,B]
    const float* tarr   = (const float*)d_in[1];  // [B]
    const float* beta   = (const float*)d_in[2];  // [B]
    const float* gamma  = (const float*)d_in[3];  // [N]
    const float* zb     = (const float*)d_in[4];  // [B,D]
    const float* zp     = (const float*)d_in[5];  // [K,N,D]
    float* out = (float*)d_out;

    float4* zbT4     = (float4*)d_ws;
    float*  coeffs   = (float*)((char*)d_ws + COEF_OFF);
    float*  partials = (float*)((char*)d_ws + PART_OFF);

    const int prep_units = ZBT_ELEMS + NN;   // 18000
    pol2vec_prep<<<(prep_units + 255) / 256, 256, 0, stream>>>(zb, zp, gamma,
                                                               zbT4, coeffs);
    dim3 grid(GX, GY);
    pol2vec_main<<<grid, TPB, 0, stream>>>(events, tarr, beta, zp, zbT4,
                                           coeffs, partials);
    pol2vec_reduce<<<1, 256, 0, stream>>>((const float4*)partials, out);
}

// Round 9
// 23.442 us; speedup vs baseline: 1.5118x; 1.3869x over previous
//
#include <hip/hip_runtime.h>
#include <hip/hip_fp16.h>
#include <math.h>

// Problem constants: N=2000 politicians, B=2000 bills, D=32, K(order)=3.
#define NN    2000
#define NB    2000
#define DD    32
#define PAD   2048                 // padded N/B for tiling
#define NOCT  12                   // 96 k-elements / 8 per fragment octet
#define TILE  64                   // block tile: 64 pols x 64 bills
#define GDIM  (PAD / TILE)         // 32
#define NPART (GDIM * GDIM)        // 1024 partials

typedef _Float16 half8  __attribute__((ext_vector_type(8)));
typedef float    float4v __attribute__((ext_vector_type(4)));

// d_ws layout (bytes):
#define ZF_OFF 0                                  // ZfF: [NOCT][PAD][8] f16 = 384KB
#define WF_OFF (NOCT * PAD * 8 * 2)               // WF:  same shape         384KB
#define BP_OFF (2 * WF_OFF)                       // bp4: float4[PAD]         32KB
#define NP_OFF (BP_OFF + PAD * 16)                // npar: float[PAD][8]      64KB
#define PT_OFF (NP_OFF + PAD * 8 * 4)             // partials: float[NPART]    4KB

// ---------------- prep: build fragment-major fp16 operands + param tables ---
// ZfF[oct][b][i]: oct 0-3 -> z_b, 4-7 -> t*z_b, 8-11 -> (t^2/2)*z_b.
// WF [oct][n][i]: oct 0-3 -> A_n, 4-7 -> B_n,   8-11 -> C_n.
// bp4[b] = {t, beta, |z_b|^2, 0};  npar[n] = {c0..c4, gamma, 0, 0} where
// |pos_n(t)|^2 = c0 + c1 t + c2 t^2 + c3 t^3 + c4 t^4.
__global__ __launch_bounds__(256) void pol2vec_prep(
    const float* __restrict__ zb, const float* __restrict__ zp,
    const float* __restrict__ gamma, const float* __restrict__ tarr,
    const float* __restrict__ beta,
    _Float16* __restrict__ ZfF, _Float16* __restrict__ WF,
    float4* __restrict__ bp4, float* __restrict__ npar)
{
    const int u = blockIdx.x * 256 + threadIdx.x;
    if (u < NOCT * PAD) {                         // ZfF entries
        const int o = u / PAD, b = u - o * PAD;
        _Float16* dst = ZfF + (size_t)u * 8;
        if (b < NB) {
            const float t = tarr[b];
            const float s = (o < 4) ? 1.f : (o < 8) ? t : 0.5f * t * t;
            const float* zrow = zb + (size_t)b * DD + 8 * (o & 3);
#pragma unroll
            for (int i = 0; i < 8; ++i) dst[i] = (_Float16)(s * zrow[i]);
        } else {
#pragma unroll
            for (int i = 0; i < 8; ++i) dst[i] = (_Float16)0.f;
        }
    } else if (u < 2 * NOCT * PAD) {              // WF entries
        const int u2 = u - NOCT * PAD;
        const int o = u2 / PAD, n = u2 - o * PAD;
        _Float16* dst = WF + (size_t)u2 * 8;
        if (n < NN) {
            const int ksel = o >> 2;              // 0:A 1:B 2:C
            const float* src = zp + ((size_t)ksel * NN + n) * DD + 8 * (o & 3);
#pragma unroll
            for (int i = 0; i < 8; ++i) dst[i] = (_Float16)src[i];
        } else {
#pragma unroll
            for (int i = 0; i < 8; ++i) dst[i] = (_Float16)0.f;
        }
    } else if (u < 2 * NOCT * PAD + PAD) {        // bill params
        const int b = u - 2 * NOCT * PAD;
        float4 v = {0.f, 0.f, 0.f, 0.f};
        if (b < NB) {
            float z2 = 0.f;
            const float* zrow = zb + (size_t)b * DD;
#pragma unroll
            for (int d = 0; d < DD; ++d) z2 = fmaf(zrow[d], zrow[d], z2);
            v.x = tarr[b]; v.y = beta[b]; v.z = z2;
        }
        bp4[b] = v;
    } else if (u < 2 * NOCT * PAD + 2 * PAD) {    // politician coeffs
        const int n = u - 2 * NOCT * PAD - PAD;
        float* o = npar + (size_t)n * 8;
        if (n < NN) {
            const float* pA = zp + (size_t)n * DD;
            const float* pB = zp + ((size_t)NN + n) * DD;
            const float* pC = zp + ((size_t)2 * NN + n) * DD;
            float aa = 0.f, ab = 0.f, ac = 0.f, bb = 0.f, bc = 0.f, cc = 0.f;
#pragma unroll
            for (int d = 0; d < DD; ++d) {
                const float a = pA[d], b = pB[d], c = pC[d];
                aa = fmaf(a, a, aa); ab = fmaf(a, b, ab); ac = fmaf(a, c, ac);
                bb = fmaf(b, b, bb); bc = fmaf(b, c, bc); cc = fmaf(c, c, cc);
            }
            o[0] = aa;         o[1] = 2.f * ab;  o[2] = bb + ac;
            o[3] = bc;         o[4] = 0.25f * cc; o[5] = gamma[n];
            o[6] = 0.f;        o[7] = 0.f;
        } else {
#pragma unroll
            for (int i = 0; i < 8; ++i) o[i] = 0.f;
        }
    }
}

// ---------------- main: fused fp16-MFMA GEMM (dot) + logistic epilogue -----
// dot[n][b] = W[n][0:96] . Zf[b][0:96]; dist^2 = poly_n(t_b) - 2 dot + |z_b|^2.
// A-operand = WF (M=pols), B-operand = ZfF (N=bills): C/D col(lane&15)=bill
// (events reads coalesced), row=(lane>>4)*4+reg = politician.
__global__ __launch_bounds__(256, 4) void pol2vec_main(
    const int* __restrict__ events,           // [N,B] 0/1
    const _Float16* __restrict__ ZfF, const _Float16* __restrict__ WF,
    const float4* __restrict__ bp4, const float* __restrict__ npar,
    float* __restrict__ partials)             // [NPART]
{
    __shared__ float4 s_bp[TILE];
    __shared__ float  s_np[TILE][8];
    __shared__ float  s_red[4];

    const int tid  = threadIdx.x;
    const int lane = tid & 63;
    const int w    = tid >> 6;                // wave 0..3
    const int b0   = blockIdx.x * TILE;       // bill base
    const int n0   = blockIdx.y * TILE;       // politician base
    const int wr   = (w >> 1) * 32;           // wave's pol offset in tile
    const int wc   = (w & 1) * 32;            // wave's bill offset in tile
    const int l15  = lane & 15;
    const int l4   = lane >> 4;

    // Stage per-tile param tables (3KB LDS).
    if (tid < TILE) s_bp[tid] = bp4[b0 + tid];
    for (int u = tid; u < TILE * 8; u += 256)
        s_np[u >> 3][u & 7] = npar[((size_t)(n0 + (u >> 3))) * 8 + (u & 7)];

    // Fragment loads: one coalesced 16B/lane load per fragment.
    half8 af[2][3], bf[2][3];
#pragma unroll
    for (int ks = 0; ks < 3; ++ks) {
        const int oct = 4 * ks + l4;
#pragma unroll
        for (int h = 0; h < 2; ++h) {
            af[h][ks] = *(const half8*)(WF  + ((size_t)oct * PAD + (n0 + wr + 16 * h + l15)) * 8);
            bf[h][ks] = *(const half8*)(ZfF + ((size_t)oct * PAD + (b0 + wc + 16 * h + l15)) * 8);
        }
    }

    // Prefetch the 16 event words -> 2 bitmask VGPRs (hides HBM under MFMA).
    unsigned evb = 0u, vb = 0u;
#pragma unroll
    for (int nr = 0; nr < 2; ++nr)
#pragma unroll
    for (int bc = 0; bc < 2; ++bc)
#pragma unroll
    for (int r = 0; r < 4; ++r) {
        const int ng = n0 + wr + 16 * nr + l4 * 4 + r;
        const int bg = b0 + wc + 16 * bc + l15;
        const bool v = (ng < NN) && (bg < NB);
        const size_t idx = v ? ((size_t)ng * NB + bg) : 0;
        const unsigned bit = 1u << (nr * 8 + bc * 4 + r);
        if (v) vb |= bit;
        if (v && events[idx]) evb |= bit;
    }

    float4v acc[2][2] = {};
#pragma unroll
    for (int nr = 0; nr < 2; ++nr)
#pragma unroll
    for (int bc = 0; bc < 2; ++bc)
#pragma unroll
    for (int ks = 0; ks < 3; ++ks)
        acc[nr][bc] = __builtin_amdgcn_mfma_f32_16x16x32_f16(
            af[nr][ks], bf[bc][ks], acc[nr][bc], 0, 0, 0);

    __syncthreads();   // param tables visible

    float accs = 0.f;
#pragma unroll
    for (int bc = 0; bc < 2; ++bc) {
        const int bl = wc + 16 * bc + l15;
        const float4 bp = s_bp[bl];
        const float t = bp.x, be = bp.y, z2 = bp.z;
#pragma unroll
        for (int nr = 0; nr < 2; ++nr) {
#pragma unroll
            for (int r = 0; r < 4; ++r) {
                const int nl = wr + 16 * nr + l4 * 4 + r;
                const float* cc = s_np[nl];
                const float dot = acc[nr][bc][r];
                const float pv = fmaf(t, fmaf(t, fmaf(t, fmaf(t, cc[4], cc[3]),
                                                      cc[2]), cc[1]), cc[0]);
                const float d2 = fmaxf(fmaf(-2.f, dot, pv + z2), 0.f);
                const float L  = cc[5] + be - sqrtf(d2);
                const unsigned bit = 1u << (nr * 8 + bc * 4 + r);
                const float sgn = (evb & bit) ? 1.f : -1.f;
                const float s   = sgn * L;
                const float term = fmaxf(-s, 0.f) + __logf(1.f + __expf(-fabsf(s)));
                accs += (vb & bit) ? term : 0.f;
            }
        }
    }

    // 256 threads -> 1 partial per block.
#pragma unroll
    for (int o = 32; o > 0; o >>= 1) accs += __shfl_down(accs, o, 64);
    if (lane == 0) s_red[w] = accs;
    __syncthreads();
    if (tid == 0)
        partials[blockIdx.y * GDIM + blockIdx.x] =
            (s_red[0] + s_red[1]) + (s_red[2] + s_red[3]);
}

// ---------------- reduce: 1024 partials -> d_out[0] ------------------------
__global__ __launch_bounds__(256) void pol2vec_reduce(
    const float4* __restrict__ p4, float* __restrict__ out)
{
    __shared__ float s_red[4];
    const int tid = threadIdx.x;
    const float4 v = p4[tid];                 // 256 threads x float4 = 1024
    float s = (v.x + v.y) + (v.z + v.w);
#pragma unroll
    for (int o = 32; o > 0; o >>= 1) s += __shfl_down(s, o, 64);
    if ((tid & 63) == 0) s_red[tid >> 6] = s;
    __syncthreads();
    if (tid == 0) out[0] = (s_red[0] + s_red[1]) + (s_red[2] + s_red[3]);
}

extern "C" void kernel_launch(void* const* d_in, const int* in_sizes, int n_in,
                              void* d_out, int out_size, void* d_ws, size_t ws_size,
                              hipStream_t stream) {
    const int*   events = (const int*)d_in[0];    // [N,B]
    const float* tarr   = (const float*)d_in[1];  // [B]
    const float* beta   = (const float*)d_in[2];  // [B]
    const float* gamma  = (const float*)d_in[3];  // [N]
    const float* zb     = (const float*)d_in[4];  // [B,D]
    const float* zp     = (const float*)d_in[5];  // [K,N,D]
    float* out = (float*)d_out;

    _Float16* ZfF   = (_Float16*)((char*)d_ws + ZF_OFF);
    _Float16* WF    = (_Float16*)((char*)d_ws + WF_OFF);
    float4*  bp4    = (float4*)((char*)d_ws + BP_OFF);
    float*   npar   = (float*)((char*)d_ws + NP_OFF);
    float*   parts  = (float*)((char*)d_ws + PT_OFF);

    const int prep_units = 2 * NOCT * PAD + 2 * PAD;   // 53248
    pol2vec_prep<<<(prep_units + 255) / 256, 256, 0, stream>>>(
        zb, zp, gamma, tarr, beta, ZfF, WF, bp4, npar);

    dim3 grid(GDIM, GDIM);
    pol2vec_main<<<grid, 256, 0, stream>>>(events, ZfF, WF, bp4, npar, parts);

    pol2vec_reduce<<<1, 256, 0, stream>>>((const float4*)parts, out);
}